// Round 5
// baseline (472.811 us; speedup 1.0000x reference)
//
#include <hip/hip_runtime.h>
#include <hip/hip_bf16.h>
#include <stdint.h>

// exp(s/sqrt(128)) = exp2(s * log2(e)/sqrt(128)); folded into Q at qk epilogue
#define SCALE_LOG2E 0.12751743f

typedef __bf16 bf16x8 __attribute__((ext_vector_type(8)));
typedef float floatx4 __attribute__((ext_vector_type(4)));
typedef uint32_t u32x4v __attribute__((ext_vector_type(4)));

__device__ __forceinline__ bf16x8 load_bf8(const void* p) {
    u32x4v v = *(const u32x4v*)p;
    return __builtin_bit_cast(bf16x8, v);
}

__device__ __forceinline__ bf16x8 cvt8(float4 u, float4 v) {
    union { bf16x8 v8; __hip_bfloat16 h[8]; } r;
    r.h[0] = __float2bfloat16(u.x); r.h[1] = __float2bfloat16(u.y);
    r.h[2] = __float2bfloat16(u.z); r.h[3] = __float2bfloat16(u.w);
    r.h[4] = __float2bfloat16(v.x); r.h[5] = __float2bfloat16(v.y);
    r.h[6] = __float2bfloat16(v.z); r.h[7] = __float2bfloat16(v.w);
    return r.v8;
}

// async 16B global -> LDS DMA (no VGPR destination; compiler cannot collapse)
__device__ __forceinline__ void dma16(const void* g, void* l) {
    __builtin_amdgcn_global_load_lds(
        (const __attribute__((address_space(1))) uint32_t*)g,
        (__attribute__((address_space(3))) uint32_t*)l, 16, 0, 0);
}

// Device-scope grid barrier. SAFE ONLY because grid (512) == guaranteed
// co-residency: __launch_bounds__(256,2) caps VGPR at 256 and LDS is
// 69632 B -> exactly 2 blocks/CU x 256 CU. atomicAdd on global memory is
// device-scope by default (crosses XCDs); __threadfence provides the
// release (writeback) / acquire (invalidate) pairing per G16.
__device__ __forceinline__ void gridbar(unsigned* cnt, unsigned target) {
    __syncthreads();
    __threadfence();                              // release my block's writes
    if (threadIdx.x == 0) {
        atomicAdd(cnt, 1u);
        while (__hip_atomic_load(cnt, __ATOMIC_RELAXED,
                                 __HIP_MEMORY_SCOPE_AGENT) < target)
            __builtin_amdgcn_s_sleep(1);
    }
    __syncthreads();
    __threadfence();                              // acquire others' writes
}

// ---------------------------------------------------------------------------
// ONE dispatch, 512 blocks x 256 threads, 4 phases split by grid barriers.
// LDS overlay: phase B uses sA 2x16KB + sC 3KB (35KB); phase C uses
// sK 2x32KB + sVS 4KB (68KB); union = 69632 B -> 2 blocks/CU.
// Phase bodies are the verified round-1 qk (+ reg-double-buffered bf16
// weights), round-3 attn (race-free (tc*2+wc) partials), round-3 final.
// ---------------------------------------------------------------------------
__global__ __launch_bounds__(256, 2) void k_mega(
        const float* __restrict__ x1, const float* __restrict__ x2,
        const float* __restrict__ w_q, const float* __restrict__ w_k,
        const float* __restrict__ w_v, const float* __restrict__ w_o,
        __hip_bfloat16* __restrict__ wq_bf, __hip_bfloat16* __restrict__ wk_bf,
        float* __restrict__ c_buf,
        __hip_bfloat16* __restrict__ Qb, __hip_bfloat16* __restrict__ Kb,
        float* __restrict__ vs_g, float* __restrict__ part,
        unsigned* __restrict__ bar, float* __restrict__ outp) {
    __shared__ alignas(16) char smem[69632];

    int bid = blockIdx.x;
    int t = threadIdx.x;
    int wave = t >> 6, lane = t & 63;
    int m = lane & 15, quad = lane >> 4;

    // ================= Phase A: weight cvt + c = w_o @ w_v =================
    if (bid < 96) {
        #pragma unroll
        for (int p = 0; p < 8; ++p) {
            int i = bid * 2048 + p * 256 + t;
            if (i < 98304) wq_bf[i] = __float2bfloat16(w_q[i]);
            else           wk_bf[i - 98304] = __float2bfloat16(w_k[i - 98304]);
        }
    } else if (bid < 99) {
        int j = (bid - 96) * 256 + t;
        float acc = 0.f;
        #pragma unroll 8
        for (int k = 0; k < 64; ++k) acc += w_o[k] * w_v[k * 768 + j];
        c_buf[j] = acc;
    }
    gridbar(&bar[0], 512);

    // ================= Phase B: Q/K GEMM + fused vs ========================
    {
        float (*sA)[32 * 128] = (float (*)[32 * 128])smem;   // 2 x 16 KB
        float* sC = (float*)(smem + 32768);                  // 3 KB

        bool isK = bid >= 256;
        int row0 = (bid & 255) * 32;
        const float* x = isK ? x2 : x1;
        const __hip_bfloat16* w = isK ? wk_bf : wq_bf;
        __hip_bfloat16* outp_b = isK ? Kb : Qb;
        int col0 = wave * 32;

        // DMA source map: tile 32 rows x 32 chunks(16B); slot s = wave*256+p*64+lane;
        // r = s>>5, pos = s&31; global chunk at pos is c = pos ^ (r&7).
        const float* gsrc[4];
        #pragma unroll
        for (int p = 0; p < 4; ++p) {
            int s = wave * 256 + p * 64 + lane;
            int r = s >> 5, pos = s & 31;
            int c = pos ^ (r & 7);
            gsrc[p] = x + (size_t)(row0 + r) * 768 + c * 4;
        }
        auto dma_tile = [&](int buf, int kc) {
            #pragma unroll
            for (int p = 0; p < 4; ++p)
                dma16(gsrc[p] + kc, &sA[buf][(wave * 256 + p * 64) * 4]);
        };

        if (isK) {  // c vector into LDS (used after loop-top barrier)
            sC[t] = c_buf[t]; sC[t + 256] = c_buf[t + 256]; sC[t + 512] = c_buf[t + 512];
        }

        const __hip_bfloat16* bp = w + (size_t)(col0 + m) * 768 + quad * 8;

        // register-double-buffered weight fragments
        bf16x8 wreg[2][8];
        #pragma unroll
        for (int j = 0; j < 2; ++j)
            #pragma unroll
            for (int ks = 0; ks < 4; ++ks)
                wreg[0][j * 4 + ks] = load_bf8(bp + (size_t)j * 16 * 768 + ks * 32);

        floatx4 acc[2][2];
        #pragma unroll
        for (int i = 0; i < 2; ++i)
            #pragma unroll
            for (int j = 0; j < 2; ++j) acc[i][j] = {0.f, 0.f, 0.f, 0.f};

        float vacc = 0.f;
        int vr = t >> 3, vh = t & 7;

        dma_tile(0, 0);

        #pragma unroll
        for (int it = 0; it < 6; ++it) {
            __syncthreads();          // drains DMAs (incl. tile it); frees buf (it+1)&1
            if (it < 5) {
                dma_tile((it + 1) & 1, (it + 1) * 128);
                #pragma unroll
                for (int j = 0; j < 2; ++j)
                    #pragma unroll
                    for (int ks = 0; ks < 4; ++ks)
                        wreg[(it + 1) & 1][j * 4 + ks] =
                            load_bf8(bp + (size_t)j * 16 * 768 + (it + 1) * 128 + ks * 32);
            }

            const float* A = sA[it & 1];
            int kc = it * 128;
            #pragma unroll
            for (int ks = 0; ks < 4; ++ks) {
                bf16x8 afr[2];
                #pragma unroll
                for (int i = 0; i < 2; ++i) {
                    int r = i * 16 + m;
                    int cb = ks * 8 + quad * 2;
                    int p0 = cb ^ (r & 7), p1 = (cb + 1) ^ (r & 7);
                    float4 f0 = *(const float4*)&A[r * 128 + p0 * 4];
                    float4 f1 = *(const float4*)&A[r * 128 + p1 * 4];
                    afr[i] = cvt8(f0, f1);
                }
                #pragma unroll
                for (int i = 0; i < 2; ++i)
                    #pragma unroll
                    for (int j = 0; j < 2; ++j)
                        acc[i][j] = __builtin_amdgcn_mfma_f32_16x16x32_bf16(
                            afr[i], wreg[it & 1][j * 4 + ks], acc[i][j], 0, 0, 0);
            }
            if (isK) {  // vs partial; swizzled chunk pos = c^(vr&7)
                #pragma unroll
                for (int cc = 0; cc < 4; ++cc) {
                    int c = vh * 4 + cc;
                    int pos = c ^ (vr & 7);
                    float4 av = *(const float4*)&A[vr * 128 + pos * 4];
                    float4 cv = *(const float4*)&sC[kc + c * 4];
                    vacc += av.x * cv.x + av.y * cv.y + av.z * cv.z + av.w * cv.w;
                }
            }
        }

        float cscale = isK ? 1.0f : SCALE_LOG2E;
        #pragma unroll
        for (int i = 0; i < 2; ++i)
            #pragma unroll
            for (int j = 0; j < 2; ++j)
                #pragma unroll
                for (int r = 0; r < 4; ++r) {
                    int row = row0 + i * 16 + quad * 4 + r;
                    int col = col0 + j * 16 + m;
                    outp_b[(size_t)row * 128 + col] = __float2bfloat16(acc[i][j][r] * cscale);
                }

        if (isK) {
            vacc += __shfl_xor(vacc, 1, 64);
            vacc += __shfl_xor(vacc, 2, 64);
            vacc += __shfl_xor(vacc, 4, 64);
            if (vh == 0) vs_g[row0 + vr] = vacc;
        }
    }
    gridbar(&bar[1], 512);

    // ================= Phase C: flash attention row-sums ===================
    {
        __hip_bfloat16 (*sK)[128 * 128] = (__hip_bfloat16 (*)[128 * 128])smem;  // 2 x 32 KB
        float* sVS = (float*)(smem + 65536);                                    // 4 KB

        int qb = bid >> 3, tc = bid & 7;
        int q0 = qb * 128, t0 = tc * 1024;
        int wr = wave >> 1, wc = wave & 1;

        bf16x8 qf[4][4];
        #pragma unroll
        for (int i = 0; i < 4; ++i)
            #pragma unroll
            for (int kk = 0; kk < 4; ++kk)
                qf[kk][i] = load_bf8(Qb + (size_t)(q0 + wr * 64 + i * 16 + m) * 128 + kk * 32 + quad * 8);

        #pragma unroll
        for (int p = 0; p < 4; ++p) sVS[p * 256 + t] = vs_g[t0 + p * 256 + t];

        // DMA source map: tile 128 rows x 16 chunks(16B); slot s = p*256+t;
        // r = s>>4, pos = s&15; chunk at pos is c = pos ^ (r&15).
        const __hip_bfloat16* gsrc[8];
        #pragma unroll
        for (int p = 0; p < 8; ++p) {
            int s = p * 256 + t;
            int r = s >> 4, pos = s & 15;
            int c = pos ^ (r & 15);
            gsrc[p] = Kb + (size_t)(t0 + r) * 128 + c * 8;
        }
        auto dma_tile = [&](int buf, int it) {
            #pragma unroll
            for (int p = 0; p < 8; ++p)
                dma16(gsrc[p] + (size_t)it * (128 * 128), &sK[buf][(p * 256 + wave * 64) * 8]);
        };

        float num_acc[4][4], den_acc[4][4];
        #pragma unroll
        for (int i = 0; i < 4; ++i)
            #pragma unroll
            for (int r = 0; r < 4; ++r) { num_acc[i][r] = 0.f; den_acc[i][r] = 0.f; }

        dma_tile(0, 0);

        for (int it = 0; it < 8; ++it) {
            __syncthreads();          // drains DMA tile it (+sVS on it=0)
            if (it < 7) dma_tile((it + 1) & 1, it + 1);
            const __hip_bfloat16* K = sK[it & 1];

            #pragma unroll
            for (int j = 0; j < 4; ++j) {
                int row = wc * 64 + j * 16 + m;
                bf16x8 bfr[4];
                #pragma unroll
                for (int kk = 0; kk < 4; ++kk)
                    bfr[kk] = load_bf8(&K[(size_t)row * 128 + (((kk * 4 + quad) ^ m) * 8)]);

                floatx4 acc[4];
                #pragma unroll
                for (int i = 0; i < 4; ++i) acc[i] = {0.f, 0.f, 0.f, 0.f};

                __builtin_amdgcn_s_setprio(1);
                #pragma unroll
                for (int kk = 0; kk < 4; ++kk)
                    #pragma unroll
                    for (int i = 0; i < 4; ++i)
                        acc[i] = __builtin_amdgcn_mfma_f32_16x16x32_bf16(qf[kk][i], bfr[kk], acc[i], 0, 0, 0);
                __builtin_amdgcn_s_setprio(0);

                float vsv = sVS[it * 128 + row];
                #pragma unroll
                for (int i = 0; i < 4; ++i)
                    #pragma unroll
                    for (int r = 0; r < 4; ++r) {
                        float p = __builtin_amdgcn_exp2f(acc[i][r]);
                        den_acc[i][r] += p;
                        num_acc[i][r] += p * vsv;
                    }
            }
        }

        int wr_ = wave >> 1;
        #pragma unroll
        for (int i = 0; i < 4; ++i)
            #pragma unroll
            for (int r = 0; r < 4; ++r) {
                float n = num_acc[i][r], d = den_acc[i][r];
                #pragma unroll
                for (int mask = 1; mask <= 8; mask <<= 1) {
                    n += __shfl_xor(n, mask, 64);
                    d += __shfl_xor(d, mask, 64);
                }
                if ((lane & 15) == 0) {
                    int row = q0 + wr_ * 64 + i * 16 + quad * 4 + r;
                    float2 p2; p2.x = n; p2.y = d;
                    // (tc*2+wc): waves 2k,2k+1 share rows, split by t-col half
                    *(float2*)&part[(size_t)row * 32 + (tc * 2 + wc) * 2] = p2;
                }
            }
    }
    gridbar(&bar[2], 512);

    // ================= Phase D: gated output ===============================
    #pragma unroll
    for (int p = 0; p < 12; ++p) {
        int idx = bid * 3072 + p * 256 + t;   // float4 index, 192 per row
        int s = idx / 192;
        float4 v = *(const float4*)(x1 + (size_t)idx * 4);
        float n = 0.f, d = 0.f;
        #pragma unroll
        for (int q = 0; q < 8; ++q) {
            float4 pq = *(const float4*)&part[(size_t)s * 32 + q * 4];
            n += pq.x + pq.z; d += pq.y + pq.w;
        }
        float g = 1.0f - n / d;
        float4 rv;
        rv.x = v.x * g; rv.y = v.y * g; rv.z = v.z * g; rv.w = v.w * g;
        *(float4*)(outp + (size_t)idx * 4) = rv;
    }
}

// ---------------------------------------------------------------------------
extern "C" void kernel_launch(void* const* d_in, const int* in_sizes, int n_in,
                              void* d_out, int out_size, void* d_ws, size_t ws_size,
                              hipStream_t stream) {
    const float* x1  = (const float*)d_in[0];
    const float* x2  = (const float*)d_in[1];
    const float* w_q = (const float*)d_in[2];
    const float* w_k = (const float*)d_in[3];
    const float* w_v = (const float*)d_in[4];
    const float* w_o = (const float*)d_in[5];
    float* outp = (float*)d_out;

    char* ws = (char*)d_ws;
    __hip_bfloat16* wq_bf = (__hip_bfloat16*)(ws + 0);        // 196608 B
    __hip_bfloat16* wk_bf = (__hip_bfloat16*)(ws + 196608);   // 196608 B
    float* c_buf          = (float*)(ws + 393216);            // 3072 B
    __hip_bfloat16* Qb    = (__hip_bfloat16*)(ws + 396288);   // 2 MB
    __hip_bfloat16* Kb    = (__hip_bfloat16*)(ws + 2493440);  // 2 MB
    float* vs_g           = (float*)(ws + 4590592);           // 32 KB
    float* part           = (float*)(ws + 4623360);           // 1 MB
    unsigned* bar         = (unsigned*)(ws + 5671936);        // 64 B

    hipMemsetAsync(bar, 0, 64, stream);   // zero barrier counters each replay
    k_mega<<<512, 256, 0, stream>>>(x1, x2, w_q, w_k, w_v, w_o,
                                    wq_bf, wk_bf, c_buf, Qb, Kb, vs_g, part,
                                    bar, outp);
}

// Round 6
// 149.382 us; speedup vs baseline: 3.1651x; 3.1651x over previous
//
#include <hip/hip_runtime.h>
#include <hip/hip_bf16.h>
#include <stdint.h>

// exp(s/sqrt(128)) = exp2(s * log2(e)/sqrt(128)); folded into Q at k_qk epilogue
#define SCALE_LOG2E 0.12751743f

typedef __bf16 bf16x8 __attribute__((ext_vector_type(8)));
typedef float floatx4 __attribute__((ext_vector_type(4)));
typedef uint32_t u32x4v __attribute__((ext_vector_type(4)));

__device__ __forceinline__ bf16x8 load_bf8(const void* p) {
    u32x4v v = *(const u32x4v*)p;
    return __builtin_bit_cast(bf16x8, v);
}

__device__ __forceinline__ bf16x8 cvt8(float4 u, float4 v) {
    union { bf16x8 v8; __hip_bfloat16 h[8]; } r;
    r.h[0] = __float2bfloat16(u.x); r.h[1] = __float2bfloat16(u.y);
    r.h[2] = __float2bfloat16(u.z); r.h[3] = __float2bfloat16(u.w);
    r.h[4] = __float2bfloat16(v.x); r.h[5] = __float2bfloat16(v.y);
    r.h[6] = __float2bfloat16(v.z); r.h[7] = __float2bfloat16(v.w);
    return r.v8;
}

// async 16B global -> LDS DMA (no VGPR destination; compiler cannot collapse)
__device__ __forceinline__ void dma16(const void* g, void* l) {
    __builtin_amdgcn_global_load_lds(
        (const __attribute__((address_space(1))) uint32_t*)g,
        (__attribute__((address_space(3))) uint32_t*)l, 16, 0, 0);
}

// ---------------------------------------------------------------------------
// Kernel A: cvt w_q,w_k -> bf16 (b<96); c[768] = w_o @ w_v (b 96..98);
// zero num/den (b 99..131; num_g/den_g contiguous 16384 floats in ws).
// ---------------------------------------------------------------------------
__global__ void k_prep(const float* __restrict__ w_q, const float* __restrict__ w_k,
                       const float* __restrict__ w_v, const float* __restrict__ w_o,
                       __hip_bfloat16* __restrict__ wq_bf,
                       __hip_bfloat16* __restrict__ wk_bf,
                       float* __restrict__ c_out,
                       float* __restrict__ numden) {
    int b = blockIdx.x;
    int t = threadIdx.x;
    if (b < 96) {
        #pragma unroll
        for (int p = 0; p < 8; ++p) {
            int i = b * 2048 + p * 256 + t;
            if (i < 98304) wq_bf[i] = __float2bfloat16(w_q[i]);
            else           wk_bf[i - 98304] = __float2bfloat16(w_k[i - 98304]);
        }
    } else if (b < 99) {
        int j = (b - 96) * 256 + t;
        float acc = 0.f;
        #pragma unroll 8
        for (int k = 0; k < 64; ++k) acc += w_o[k] * w_v[k * 768 + j];
        c_out[j] = acc;
    } else {
        int z = (b - 99) * 512 + t * 2;
        if (z < 16384) { numden[z] = 0.f; numden[z + 1] = 0.f; }
    }
}

// ---------------------------------------------------------------------------
// Kernel B: Q = x1 @ w_q^T * SCALE (bid 0..255), K = x2 @ w_k^T (256..511).
// vs = x2 . c fused into the K blocks. m97-style: block = 32 rows x 128 cols,
// BK=128, 6 K-iters, A-tile double-buffered via global_load_lds width=16,
// XOR-swizzled (c^(r&7)) at the global source.
// ROUND-6 CHANGE (only delta vs the 148.3 µs round-1 artifact): weight
// fragments are REGISTER-DOUBLE-BUFFERED (wreg[2][8]; iter it+1's 8 L2
// loads issue under iter it's MFMA). Round-3 counters showed VGPR=56,
// CPI~10: the compiler had placed these loads at their uses, putting an
// L2-latency chain on the MFMA critical path. launch_bounds relaxed to
// (256,2): grid 512 = 2 blocks/CU is the occupancy bound regardless, so
// a 128-VGPR cap only forces under-allocation; this gives the prefetch
// buffer (64 VGPR) room.
// ---------------------------------------------------------------------------
__global__ __launch_bounds__(256, 2) void k_qk(
        const float* __restrict__ x1, const float* __restrict__ x2,
        const __hip_bfloat16* __restrict__ wq_bf,
        const __hip_bfloat16* __restrict__ wk_bf,
        const float* __restrict__ c_in,
        __hip_bfloat16* __restrict__ Qb, __hip_bfloat16* __restrict__ Kb,
        float* __restrict__ vs_g) {
    __shared__ alignas(16) float sA[2][32 * 128];  // 2 x 16 KB, swizzled 16B chunks

    int bid = blockIdx.x;
    int t = threadIdx.x;

    bool isK = bid >= 256;
    int row0 = (bid & 255) * 32;
    const float* x = isK ? x2 : x1;
    const __hip_bfloat16* w = isK ? wk_bf : wq_bf;
    __hip_bfloat16* outp = isK ? Kb : Qb;

    int wave = t >> 6, lane = t & 63;
    int m = lane & 15, quad = lane >> 4;
    int col0 = wave * 32;

    // Per-thread DMA source mapping (constant across iters, only kc changes).
    // Tile = 32 rows x 32 chunks (16B). Slot s = wave*256 + p*64 + lane.
    // r = s>>5, pos = s&31; global chunk stored at pos is c = pos ^ (r&7).
    const float* gsrc[4];
    #pragma unroll
    for (int p = 0; p < 4; ++p) {
        int s = wave * 256 + p * 64 + lane;
        int r = s >> 5, pos = s & 31;
        int c = pos ^ (r & 7);
        gsrc[p] = x + (size_t)(row0 + r) * 768 + c * 4;
    }
    // wave-uniform LDS bases for the 4 DMA instructions (HW adds lane*16)
    auto dma_tile = [&](int buf, int kc) {
        #pragma unroll
        for (int p = 0; p < 4; ++p)
            dma16(gsrc[p] + kc, &sA[buf][(wave * 256 + p * 64) * 4]);
    };

    const __hip_bfloat16* bp = w + (size_t)(col0 + m) * 768 + quad * 8;

    // register-double-buffered weight fragments: wreg[parity][j*4+ks]
    bf16x8 wreg[2][8];
    #pragma unroll
    for (int j = 0; j < 2; ++j)
        #pragma unroll
        for (int ks = 0; ks < 4; ++ks)
            wreg[0][j * 4 + ks] = load_bf8(bp + (size_t)j * 16 * 768 + ks * 32);

    floatx4 acc[2][2];
    #pragma unroll
    for (int i = 0; i < 2; ++i)
        #pragma unroll
        for (int j = 0; j < 2; ++j) acc[i][j] = {0.f, 0.f, 0.f, 0.f};

    // fused-vs state (K blocks): thread owns row vr, 16B chunks vh*4..vh*4+3
    float vacc = 0.f;
    int vr = t >> 3, vh = t & 7;

    dma_tile(0, 0);

    for (int it = 0; it < 6; ++it) {
        __syncthreads();            // drains all DMAs (incl. tile it); frees buf (it+1)&1
        if (it < 5) {
            dma_tile((it + 1) & 1, (it + 1) * 128);
            // prefetch next iter's weight fragments (hidden under this iter's MFMA)
            #pragma unroll
            for (int j = 0; j < 2; ++j)
                #pragma unroll
                for (int ks = 0; ks < 4; ++ks)
                    wreg[(it + 1) & 1][j * 4 + ks] =
                        load_bf8(bp + (size_t)j * 16 * 768 + (it + 1) * 128 + ks * 32);
        }

        const float* A = sA[it & 1];
        int kc = it * 128;
        #pragma unroll
        for (int ks = 0; ks < 4; ++ks) {
            bf16x8 afr[2];
            #pragma unroll
            for (int i = 0; i < 2; ++i) {
                int r = i * 16 + m;
                int cb = ks * 8 + quad * 2;
                int p0 = cb ^ (r & 7), p1 = (cb + 1) ^ (r & 7);
                float4 f0 = *(const float4*)&A[r * 128 + p0 * 4];
                float4 f1 = *(const float4*)&A[r * 128 + p1 * 4];
                afr[i] = cvt8(f0, f1);
            }
            #pragma unroll
            for (int i = 0; i < 2; ++i)
                #pragma unroll
                for (int j = 0; j < 2; ++j)
                    acc[i][j] = __builtin_amdgcn_mfma_f32_16x16x32_bf16(
                        afr[i], wreg[it & 1][j * 4 + ks], acc[i][j], 0, 0, 0);
        }
        if (isK) {
            // vs partial from the staged tile (reads finish before buf reuse:
            // they precede the barrier of it+1). Swizzled chunk pos = c^(vr&7).
            #pragma unroll
            for (int cc = 0; cc < 4; ++cc) {
                int c = vh * 4 + cc;
                int pos = c ^ (vr & 7);
                float4 av = *(const float4*)&A[vr * 128 + pos * 4];
                float4 cv = *(const float4*)&c_in[kc + c * 4];
                vacc += av.x * cv.x + av.y * cv.y + av.z * cv.z + av.w * cv.w;
            }
        }
    }

    // write C (bf16); Q side pre-scaled. C layout: col=lane&15, row=quad*4+reg
    float cscale = isK ? 1.0f : SCALE_LOG2E;
    #pragma unroll
    for (int i = 0; i < 2; ++i)
        #pragma unroll
        for (int j = 0; j < 2; ++j)
            #pragma unroll
            for (int r = 0; r < 4; ++r) {
                int row = row0 + i * 16 + quad * 4 + r;
                int col = col0 + j * 16 + m;
                outp[(size_t)row * 128 + col] = __float2bfloat16(acc[i][j][r] * cscale);
            }

    if (isK) {
        // reduce vs over the 8 vh lanes (adjacent within wave) and store
        vacc += __shfl_xor(vacc, 1, 64);
        vacc += __shfl_xor(vacc, 2, 64);
        vacc += __shfl_xor(vacc, 4, 64);
        if (vh == 0) vs_g[row0 + vr] = vacc;
    }
}

// ---------------------------------------------------------------------------
// Kernel C: flash-style attention row-sums. Q-fragments in registers
// (loop-invariant); K tile round-trips LDS with register prefetch.
// grid 512 = 64 q-blocks x 8 t-chunks. p = exp2(S) since Q pre-scaled.
// (byte-identical to the 148.3 µs round-1 artifact)
// ---------------------------------------------------------------------------
__global__ __launch_bounds__(256, 2) void k_attn(
        const __hip_bfloat16* __restrict__ Qb, const __hip_bfloat16* __restrict__ Kb,
        const float* __restrict__ vs_g,
        float* __restrict__ num_g, float* __restrict__ den_g) {
    constexpr int LDK = 136;  // 128 + 8 pad
    __shared__ alignas(16) __hip_bfloat16 sK[128 * LDK];
    __shared__ float sVS[1024];

    int bid = blockIdx.x;
    int qb = bid >> 3, tc = bid & 7;
    int q0 = qb * 128, t0 = tc * 1024;

    int t = threadIdx.x;
    int wave = t >> 6, lane = t & 63;
    int wr = wave >> 1, wc = wave & 1;
    int m = lane & 15, quad = lane >> 4;

    bf16x8 qf[4][4];
    #pragma unroll
    for (int i = 0; i < 4; ++i)
        #pragma unroll
        for (int kk = 0; kk < 4; ++kk)
            qf[kk][i] = load_bf8(Qb + (size_t)(q0 + wr * 64 + i * 16 + m) * 128 + kk * 32 + quad * 8);

    #pragma unroll
    for (int p = 0; p < 4; ++p) sVS[p * 256 + t] = vs_g[t0 + p * 256 + t];

    u32x4v kreg[8];
    #pragma unroll
    for (int p = 0; p < 8; ++p) {
        int f = p * 256 + t;
        int r = f >> 4, c = (f & 15) * 8;
        kreg[p] = *(const u32x4v*)(Kb + (size_t)(t0 + r) * 128 + c);
    }

    float num_acc[4][4], den_acc[4][4];
    #pragma unroll
    for (int i = 0; i < 4; ++i)
        #pragma unroll
        for (int r = 0; r < 4; ++r) { num_acc[i][r] = 0.f; den_acc[i][r] = 0.f; }

    for (int it = 0; it < 8; ++it) {
        __syncthreads();
        #pragma unroll
        for (int p = 0; p < 8; ++p) {
            int f = p * 256 + t;
            int r = f >> 4, c = (f & 15) * 8;
            *(u32x4v*)(&sK[r * LDK + c]) = kreg[p];
        }
        __syncthreads();
        if (it < 7) {
            #pragma unroll
            for (int p = 0; p < 8; ++p) {
                int f = p * 256 + t;
                int r = f >> 4, c = (f & 15) * 8;
                kreg[p] = *(const u32x4v*)(Kb + (size_t)(t0 + (it + 1) * 128 + r) * 128 + c);
            }
        }

        floatx4 acc[4][4];
        #pragma unroll
        for (int i = 0; i < 4; ++i)
            #pragma unroll
            for (int j = 0; j < 4; ++j) acc[i][j] = {0.f, 0.f, 0.f, 0.f};

        #pragma unroll
        for (int kk = 0; kk < 4; ++kk) {
            bf16x8 bfr[4];
            #pragma unroll
            for (int j = 0; j < 4; ++j)
                bfr[j] = load_bf8(&sK[(wc * 64 + j * 16 + m) * LDK + kk * 32 + quad * 8]);
            #pragma unroll
            for (int i = 0; i < 4; ++i)
                #pragma unroll
                for (int j = 0; j < 4; ++j)
                    acc[i][j] = __builtin_amdgcn_mfma_f32_16x16x32_bf16(qf[kk][i], bfr[j], acc[i][j], 0, 0, 0);
        }

        #pragma unroll
        for (int j = 0; j < 4; ++j) {
            float vsv = sVS[it * 128 + wc * 64 + j * 16 + m];
            #pragma unroll
            for (int i = 0; i < 4; ++i)
                #pragma unroll
                for (int r = 0; r < 4; ++r) {
                    float p = __builtin_amdgcn_exp2f(acc[i][j][r]);
                    den_acc[i][r] += p;
                    num_acc[i][r] += p * vsv;
                }
        }
    }

    #pragma unroll
    for (int i = 0; i < 4; ++i)
        #pragma unroll
        for (int r = 0; r < 4; ++r) {
            float n = num_acc[i][r], d = den_acc[i][r];
            #pragma unroll
            for (int mask = 1; mask <= 8; mask <<= 1) {
                n += __shfl_xor(n, mask, 64);
                d += __shfl_xor(d, mask, 64);
            }
            if ((lane & 15) == 0) {
                int row = q0 + wr * 64 + i * 16 + quad * 4 + r;
                atomicAdd(&num_g[row], n);
                atomicAdd(&den_g[row], d);
            }
        }
}

// ---------------------------------------------------------------------------
// Kernel D: gated = x1 * (1 - num/den). float4 grid-mapped, memory-bound.
// ---------------------------------------------------------------------------
__global__ void k_final(const float* __restrict__ x1,
                        const float* __restrict__ num_g,
                        const float* __restrict__ den_g,
                        float* __restrict__ outp) {
    int idx = blockIdx.x * 256 + threadIdx.x;  // float4 index, 192 per row
    int s = idx / 192;
    float4 v = *(const float4*)(x1 + (size_t)idx * 4);
    float g = 1.0f - num_g[s] / den_g[s];
    float4 rv;
    rv.x = v.x * g; rv.y = v.y * g; rv.z = v.z * g; rv.w = v.w * g;
    *(float4*)(outp + (size_t)idx * 4) = rv;
}

// ---------------------------------------------------------------------------
extern "C" void kernel_launch(void* const* d_in, const int* in_sizes, int n_in,
                              void* d_out, int out_size, void* d_ws, size_t ws_size,
                              hipStream_t stream) {
    const float* x1  = (const float*)d_in[0];
    const float* x2  = (const float*)d_in[1];
    const float* w_q = (const float*)d_in[2];
    const float* w_k = (const float*)d_in[3];
    const float* w_v = (const float*)d_in[4];
    const float* w_o = (const float*)d_in[5];
    float* outp = (float*)d_out;

    char* ws = (char*)d_ws;
    __hip_bfloat16* wq_bf = (__hip_bfloat16*)(ws + 0);        // 196608 B
    __hip_bfloat16* wk_bf = (__hip_bfloat16*)(ws + 196608);   // 196608 B
    float* c_buf          = (float*)(ws + 393216);            // 3072 B
    __hip_bfloat16* Qb    = (__hip_bfloat16*)(ws + 396288);   // 2 MB
    __hip_bfloat16* Kb    = (__hip_bfloat16*)(ws + 2493440);  // 2 MB
    float* vs_g           = (float*)(ws + 4590592);           // 32 KB
    float* num_g          = (float*)(ws + 4623360);           // 32 KB
    float* den_g          = (float*)(ws + 4656128);           // 32 KB (contig after num_g)

    k_prep<<<132, 256, 0, stream>>>(w_q, w_k, w_v, w_o, wq_bf, wk_bf, c_buf, num_g);
    k_qk<<<512, 256, 0, stream>>>(x1, x2, wq_bf, wk_bf, c_buf, Qb, Kb, vs_g);
    k_attn<<<512, 256, 0, stream>>>(Qb, Kb, vs_g, num_g, den_g);
    k_final<<<6144, 256, 0, stream>>>(x1, num_g, den_g, outp);
}